// Round 2
// baseline (202.905 us; speedup 1.0000x reference)
//
#include <hip/hip_runtime.h>
#include <cfloat>
#include <climits>

// Problem constants (from reference)
#define Nn 32
#define Qq 300
#define Cc 92
#define Tt 32

// ---------------------------------------------------------------------------
// Kernel 1: compute two cost blocks per batch i:
//   diag[i][t][q]  = cost(query (i,q), target i*T+t)   -> used by LSA
//   cross[i][t][q] = cost(query (i,q), target t)       -> used by final sum
//     (reference quirk: mult[i, q_of_t, arange(T)] indexes GLOBAL cols 0..31,
//      i.e. batch 0's targets, while the assignment comes from the diagonal)
// One block per batch, one thread per query.
// ---------------------------------------------------------------------------
__global__ __launch_bounds__(320) void cost_kernel(
    const float* __restrict__ logits,   // [N,Q,C]
    const float* __restrict__ pboxes,   // [N,Q,4] cxcywh
    const int*   __restrict__ tlabels,  // [N*T]
    const float* __restrict__ tboxes,   // [N*T,4] cxcywh
    float* __restrict__ diag,           // [N,T,Q]
    float* __restrict__ cross)          // [N,T,Q]
{
    const int i = blockIdx.x;
    const int q = threadIdx.x;

    __shared__ float s_tb[Tt * 4];   // batch i targets
    __shared__ int   s_tl[Tt];
    __shared__ float s_tb0[Tt * 4];  // global targets 0..31 (batch 0)
    __shared__ int   s_tl0[Tt];
    if (q < Tt * 4) { s_tb[q] = tboxes[i * Tt * 4 + q]; s_tb0[q] = tboxes[q]; }
    if (q < Tt)     { s_tl[q] = tlabels[i * Tt + q];    s_tl0[q] = tlabels[q]; }
    __syncthreads();

    if (q >= Qq) return;

    // softmax over C=92 classes for this (i,q)
    const float* lg = logits + ((size_t)(i * Qq + q)) * Cc;
    float mx = -FLT_MAX;
    for (int c = 0; c < Cc; ++c) mx = fmaxf(mx, lg[c]);
    float s = 0.f;
    for (int c = 0; c < Cc; ++c) s += expf(lg[c] - mx);
    const float inv_s = 1.f / s;

    const float* pb = pboxes + ((size_t)(i * Qq + q)) * 4;
    const float cx = pb[0], cy = pb[1], w = pb[2], h = pb[3];
    const float ax0 = cx - 0.5f * w, ay0 = cy - 0.5f * h;
    const float ax1 = cx + 0.5f * w, ay1 = cy + 0.5f * h;
    const float areaA = (ax1 - ax0) * (ay1 - ay0);

    for (int t = 0; t < Tt; ++t) {
        // two target sets: k=0 -> diag (batch i), k=1 -> cross (batch 0)
        for (int k = 0; k < 2; ++k) {
            const float* tb = k ? s_tb0 : s_tb;
            const int*   tl = k ? s_tl0 : s_tl;

            const float bcx = tb[t * 4 + 0], bcy = tb[t * 4 + 1];
            const float bw  = tb[t * 4 + 2], bh  = tb[t * 4 + 3];

            const float l1 = fabsf(cx - bcx) + fabsf(cy - bcy) +
                             fabsf(w - bw) + fabsf(h - bh);

            const float bx0 = bcx - 0.5f * bw, by0 = bcy - 0.5f * bh;
            const float bx1 = bcx + 0.5f * bw, by1 = bcy + 0.5f * bh;
            const float areaB = (bx1 - bx0) * (by1 - by0);

            const float ltx = fmaxf(ax0, bx0), lty = fmaxf(ay0, by0);
            const float rbx = fminf(ax1, bx1), rby = fminf(ay1, by1);
            const float iw = fmaxf(rbx - ltx, 0.f), ih = fmaxf(rby - lty, 0.f);
            const float inter = iw * ih;
            const float uni = areaA + areaB - inter;
            const float iou = inter / uni;

            const float ex0 = fminf(ax0, bx0), ey0 = fminf(ay0, by0);
            const float ex1 = fmaxf(ax1, bx1), ey1 = fmaxf(ey1 - ey0, 0.f) * 0.f + fmaxf(ay1, by1);
            const float ew = fmaxf(ex1 - ex0, 0.f), eh = fmaxf(fmaxf(ay1, by1) - ey0, 0.f);
            const float areaC = ew * eh;
            const float giou = iou - (areaC - uni) / areaC;

            const float cls = -expf(lg[tl[t]] - mx) * inv_s;

            const float cv = 5.f * l1 + cls - 2.f * giou;
            float* dst = k ? cross : diag;
            dst[((size_t)(i * Tt + t)) * Qq + q] = cv;
        }
    }
}

// ---------------------------------------------------------------------------
// Kernel 2: per-batch Hungarian (Jonker-Volgenant, mirrors reference _lsa).
// One single-wave (64-thread) block per batch. Diagonal cost block (32x300
// f32) and dual variables (f64, matching numpy's float64 promotion) in LDS.
// Final sum gathers from the CROSS block (reference's arange(T) quirk).
// ---------------------------------------------------------------------------
__global__ __launch_bounds__(64) void lsa_kernel(
    const float* __restrict__ diag,   // [N,T,Q]
    const float* __restrict__ cross,  // [N,T,Q]
    float* __restrict__ out)          // scalar accumulator (pre-zeroed)
{
    const int b = blockIdx.x;
    const int lane = threadIdx.x;

    __shared__ float  cst[Tt * Qq];        // 38400 B
    __shared__ double v[Qq + 1];
    __shared__ double minv[Qq + 1];
    __shared__ double u[Tt + 1];
    __shared__ int    p[Qq + 1];
    __shared__ int    way[Qq + 1];
    __shared__ int    used[Qq + 1];

    for (int k = lane; k < Tt * Qq; k += 64) cst[k] = diag[(size_t)b * Tt * Qq + k];
    for (int k = lane; k <= Qq; k += 64) { v[k] = 0.0; p[k] = 0; way[k] = 0; }
    if (lane <= Tt) u[lane] = 0.0;
    __syncthreads();

    for (int i = 1; i <= Tt; ++i) {
        for (int k = lane; k <= Qq; k += 64) { minv[k] = DBL_MAX; used[k] = 0; }
        if (lane == 0) p[0] = i;
        __syncthreads();

        int j0 = 0;  // uniform across lanes
        while (true) {
            if (lane == 0) used[j0] = 1;
            __syncthreads();

            const int i0 = p[j0];        // broadcast LDS read
            const double ui0 = u[i0];

            double val = DBL_MAX;
            int idx = INT_MAX;
            // min phase: columns j = lane+1, lane+1+64, ...
            for (int j = lane + 1; j <= Qq; j += 64) {
                if (!used[j]) {
                    const double cur =
                        (double)cst[(i0 - 1) * Qq + (j - 1)] - ui0 - v[j];
                    if (cur < minv[j]) { minv[j] = cur; way[j] = j0; }
                    const double mj = minv[j];
                    if (mj < val) { val = mj; idx = j; }  // ascending j: smallest idx on tie
                }
            }
            // wave argmin (value, then smallest index on ties)
            for (int off = 32; off > 0; off >>= 1) {
                const double ov = __shfl_down(val, off);
                const int    oi = __shfl_down(idx, off);
                if (ov < val || (ov == val && oi < idx)) { val = ov; idx = oi; }
            }
            const double delta = __shfl(val, 0);
            const int    j1    = __shfl(idx, 0);
            __syncthreads();  // min-phase mapping -> update-phase mapping

            // update phase: columns j = lane, lane+64, ...
            for (int j = lane; j <= Qq; j += 64) {
                if (used[j]) {
                    u[p[j]] += delta;   // distinct rows across used columns
                    v[j]    -= delta;
                } else if (j >= 1) {
                    minv[j] -= delta;
                }
            }
            __syncthreads();

            j0 = j1;
            if (p[j0] == 0) break;  // uniform: p unchanged inside the loop
        }

        // augment along the path (serial, short)
        if (lane == 0) {
            int jj = j0;
            while (jj) {
                const int jprev = way[jj];
                p[jj] = p[jprev];
                jj = jprev;
            }
        }
        __syncthreads();
    }

    // Final gather: matched pair (row t = p[j]-1, col q = j-1) but cost taken
    // from the CROSS block: cross[b][t][q].
    float part = 0.f;
    for (int j = lane + 1; j <= Qq; j += 64) {
        const int r = p[j];
        if (r) part += cross[(size_t)b * Tt * Qq + (size_t)(r - 1) * Qq + (j - 1)];
    }
    for (int off = 32; off > 0; off >>= 1) part += __shfl_down(part, off);
    if (lane == 0) atomicAdd(out, part);
}

extern "C" void kernel_launch(void* const* d_in, const int* in_sizes, int n_in,
                              void* d_out, int out_size, void* d_ws, size_t ws_size,
                              hipStream_t stream) {
    const float* logits  = (const float*)d_in[0];   // [32,300,92] f32
    const float* pboxes  = (const float*)d_in[1];   // [32,300,4]  f32
    const int*   tlabels = (const int*)d_in[2];     // [1024]      int
    const float* tboxes  = (const float*)d_in[3];   // [1024,4]    f32
    float* out = (float*)d_out;                     // scalar f32
    float* diag  = (float*)d_ws;                            // [32,32,300]
    float* cross = (float*)d_ws + (size_t)Nn * Tt * Qq;     // [32,32,300]

    hipMemsetAsync(out, 0, sizeof(float), stream);
    cost_kernel<<<Nn, 320, 0, stream>>>(logits, pboxes, tlabels, tboxes, diag, cross);
    lsa_kernel<<<Nn, 64, 0, stream>>>(diag, cross, out);
}

// Round 3
// 131.005 us; speedup vs baseline: 1.5488x; 1.5488x over previous
//
#include <hip/hip_runtime.h>
#include <cfloat>

// Problem constants (from reference)
#define Nn 32
#define Qq 300
#define Cc 92
#define Tt 32
#define KCOLS 5   // ceil(300/64) columns owned per lane

// ---------------------------------------------------------------------------
// DPP full-wave (64-lane) float min, broadcast to all lanes.
// row_shr 1/2/4/8 -> lanes 15/31/47/63 hold row minima; row_bcast15 merges
// row pairs; row_bcast31 merges halves; lane 63 holds the wave min.
// update_dpp(old=own, ..., bound_ctrl=false): invalid source lanes return own
// value -> identity for min.
// ---------------------------------------------------------------------------
__device__ inline float wave_min_bcast(float x) {
#define DPPMIN(ctrl) { int _t = __builtin_amdgcn_update_dpp( \
        __float_as_int(x), __float_as_int(x), ctrl, 0xf, 0xf, false); \
        x = fminf(x, __int_as_float(_t)); }
    DPPMIN(0x111) DPPMIN(0x112) DPPMIN(0x114) DPPMIN(0x118)
    DPPMIN(0x142) DPPMIN(0x143)
#undef DPPMIN
    return __int_as_float(__builtin_amdgcn_readlane(__float_as_int(x), 63));
}

// Select a[k] for runtime k without scratch spill (cndmask chain).
__device__ inline int sel5i(const int a[KCOLS], int k) {
    int r = a[0];
    if (k == 1) r = a[1];
    if (k == 2) r = a[2];
    if (k == 3) r = a[3];
    if (k == 4) r = a[4];
    return r;
}

// ---------------------------------------------------------------------------
// Kernel 1: diagonal + cross cost blocks (see round-1 notes: the reference's
// mult[i, q_of_t, arange(T)] sums costs against GLOBAL targets 0..31).
// One thread per (batch, query). Logits loaded once as 23 float4.
// ---------------------------------------------------------------------------
__global__ __launch_bounds__(320) void cost_kernel(
    const float* __restrict__ logits,   // [N,Q,C]
    const float* __restrict__ pboxes,   // [N,Q,4] cxcywh
    const int*   __restrict__ tlabels,  // [N*T]
    const float* __restrict__ tboxes,   // [N*T,4] cxcywh
    float* __restrict__ diag,           // [N,T,Q]
    float* __restrict__ cross)          // [N,T,Q]
{
    const int i = blockIdx.x;
    const int q = threadIdx.x;

    __shared__ float s_tb[2][Tt * 4];   // [0]=batch-i targets, [1]=global 0..31
    __shared__ int   s_tl[2][Tt];
    if (q < Tt * 4) { s_tb[0][q] = tboxes[i * Tt * 4 + q]; s_tb[1][q] = tboxes[q]; }
    if (q < Tt)     { s_tl[0][q] = tlabels[i * Tt + q];    s_tl[1][q] = tlabels[q]; }
    __syncthreads();
    if (q >= Qq) return;

    // --- softmax over C=92, single pass of vector loads ---
    const float* lg = logits + (size_t)(i * Qq + q) * Cc;   // 368 B, 16B-aligned
    float4 r[23];
#pragma unroll
    for (int c = 0; c < 23; ++c) r[c] = reinterpret_cast<const float4*>(lg)[c];

    float mx = -FLT_MAX;
#pragma unroll
    for (int c = 0; c < 23; ++c)
        mx = fmaxf(mx, fmaxf(fmaxf(r[c].x, r[c].y), fmaxf(r[c].z, r[c].w)));
    float s = 0.f;
#pragma unroll
    for (int c = 0; c < 23; ++c)
        s += __expf(r[c].x - mx) + __expf(r[c].y - mx) +
             __expf(r[c].z - mx) + __expf(r[c].w - mx);
    const float inv_s = 1.f / s;

    const float4 pbv = reinterpret_cast<const float4*>(pboxes)[i * Qq + q];
    const float cx = pbv.x, cy = pbv.y, w = pbv.z, h = pbv.w;
    const float ax0 = cx - 0.5f * w, ay0 = cy - 0.5f * h;
    const float ax1 = cx + 0.5f * w, ay1 = cy + 0.5f * h;
    const float areaA = (ax1 - ax0) * (ay1 - ay0);

    for (int t = 0; t < Tt; ++t) {
#pragma unroll
        for (int k = 0; k < 2; ++k) {
            const float bcx = s_tb[k][t * 4 + 0], bcy = s_tb[k][t * 4 + 1];
            const float bw  = s_tb[k][t * 4 + 2], bh  = s_tb[k][t * 4 + 3];

            const float l1 = fabsf(cx - bcx) + fabsf(cy - bcy) +
                             fabsf(w - bw) + fabsf(h - bh);

            const float bx0 = bcx - 0.5f * bw, by0 = bcy - 0.5f * bh;
            const float bx1 = bcx + 0.5f * bw, by1 = bcy + 0.5f * bh;
            const float areaB = (bx1 - bx0) * (by1 - by0);

            const float ltx = fmaxf(ax0, bx0), lty = fmaxf(ay0, by0);
            const float rbx = fminf(ax1, bx1), rby = fminf(ay1, by1);
            const float iw = fmaxf(rbx - ltx, 0.f), ih = fmaxf(rby - lty, 0.f);
            const float inter = iw * ih;
            const float uni = areaA + areaB - inter;
            const float iou = inter / uni;

            const float ex0 = fminf(ax0, bx0), ey0 = fminf(ay0, by0);
            const float ex1 = fmaxf(ax1, bx1), ey1 = fmaxf(ay1, by1);
            const float ew = fmaxf(ex1 - ex0, 0.f), eh = fmaxf(ey1 - ey0, 0.f);
            const float areaC = ew * eh;
            const float giou = iou - (areaC - uni) / areaC;

            const float cls = -__expf(lg[s_tl[k][t]] - mx) * inv_s;  // L1/L2-hot reload

            const float cv = 5.f * l1 + cls - 2.f * giou;
            float* dst = k ? cross : diag;
            dst[((size_t)(i * Tt + t)) * Qq + q] = cv;
        }
    }
}

// ---------------------------------------------------------------------------
// Kernel 2: per-batch Jonker-Volgenant LSA, deferred-dual (scipy-lapjv style)
// formulation — algebraically identical assignment to the reference's e-maxx
// loop. One single-wave block per batch.
//   - per-column state (v, minv, way, p, used) in REGISTERS (lane owns
//     columns j-1 = lane + 64k, k<5) -> zero LDS writes / barriers in the
//     Dijkstra loop.
//   - argmin: DPP v_min_f32 chain + ballot + one packed 64-bit shuffle that
//     returns both j1 and its matched row.
//   - duals patched once per row from frozen minv values:
//       used col j: v[j] -= Dfinal - minv[j]; u[p[j]] += Dfinal - minv[j]
//       start row i: u[i] += Dfinal
// ---------------------------------------------------------------------------
__global__ __launch_bounds__(64, 1) void lsa_kernel(
    const float* __restrict__ diag,   // [N,T,Q]
    const float* __restrict__ cross,  // [N,T,Q]
    float* __restrict__ out)          // scalar accumulator (pre-zeroed)
{
    const int b = blockIdx.x;
    const int lane = threadIdx.x;

    __shared__ float cst[Tt * Qq];    // 38400 B
    __shared__ float u[Tt + 1];

    for (int k = lane; k < Tt * Qq; k += 64) cst[k] = diag[(size_t)b * Tt * Qq + k];
    if (lane <= Tt) u[lane] = 0.f;

    float v_r[KCOLS], minv_r[KCOLS];
    int way_r[KCOLS], p_r[KCOLS], used_r[KCOLS];
    bool valid[KCOLS];
#pragma unroll
    for (int k = 0; k < KCOLS; ++k) {
        valid[k] = (lane + 64 * k) < Qq;
        v_r[k] = 0.f; p_r[k] = 0;
    }
    __syncthreads();

    for (int i = 1; i <= Tt; ++i) {
#pragma unroll
        for (int k = 0; k < KCOLS; ++k) { minv_r[k] = FLT_MAX; way_r[k] = 0; used_r[k] = 0; }

        int   j0 = 0;
        int   i0 = i;
        float dent = 0.f;        // cumulative delta when i0 entered
        float u_i0 = u[i0];      // u frozen at row-loop start (deferred duals)
        int   jfinal = 0;
        float Dfinal = 0.f;

        while (true) {
            // --- scan phase: update minv over free columns; local candidate ---
            float val = FLT_MAX;
            int idx = 0, kb = 0;
            const int rowbase = (i0 - 1) * Qq;
#pragma unroll
            for (int k = 0; k < KCOLS; ++k) {
                if (valid[k] && !used_r[k]) {
                    const int j = lane + 64 * k;            // 0-based column
                    const float cur = dent + cst[rowbase + j] - u_i0 - v_r[k];
                    if (cur < minv_r[k]) { minv_r[k] = cur; way_r[k] = j0; }
                    if (minv_r[k] < val) { val = minv_r[k]; idx = j + 1; kb = k; }
                }
            }
            // --- wave argmin ---
            const float gmin = wave_min_bcast(val);
            const unsigned long long mask = __ballot(val == gmin);
            const int src = __ffsll((long long)mask) - 1;
            // owner packs (matched row of its candidate col, col index)
            const unsigned long long pk =
                ((unsigned long long)(unsigned)sel5i(p_r, kb) << 32) | (unsigned)idx;
            const unsigned long long got = __shfl(pk, src);
            const int j1   = (int)(got & 0xffffffffu);
            const int rowm = (int)(got >> 32);

            // mark j1 used at its owner lane (k1 uniform; write via unrolled select)
            const int k1 = (j1 - 1) >> 6;
            const bool own = (lane == ((j1 - 1) & 63));
#pragma unroll
            for (int k = 0; k < KCOLS; ++k) if (own && k == k1) used_r[k] = 1;

            if (rowm == 0) { jfinal = j1; Dfinal = gmin; break; }
            j0 = j1; i0 = rowm; dent = gmin; u_i0 = u[i0];
        }

        // --- dual updates (pre-augment p), one shot per row ---
#pragma unroll
        for (int k = 0; k < KCOLS; ++k) {
            if (used_r[k]) {
                const float dm = Dfinal - minv_r[k];
                v_r[k] -= dm;
                u[p_r[k]] += dm;          // distinct rows -> no collisions
            }
        }
        if (lane == 0) u[i] += Dfinal;
        __syncthreads();                  // u visible for next row

        // --- augment along the path (short; register/shuffle walk) ---
        int jj = jfinal;
        while (jj) {
            const int ow = (jj - 1) & 63, kk = (jj - 1) >> 6;
            const int jprev = __shfl(sel5i(way_r, kk), ow);   // uniform
            int pnew;
            if (jprev == 0) pnew = i;
            else {
                const int ow2 = (jprev - 1) & 63, k2 = (jprev - 1) >> 6;
                pnew = __shfl(sel5i(p_r, k2), ow2);
            }
            const bool own = (lane == ow);
#pragma unroll
            for (int k = 0; k < KCOLS; ++k) if (own && k == kk) p_r[k] = pnew;
            jj = jprev;
        }
    }

    // --- final gather: pair (t = p[j]-1, q = j-1) from the CROSS block ---
    float part = 0.f;
#pragma unroll
    for (int k = 0; k < KCOLS; ++k) {
        if (valid[k] && p_r[k]) {
            const int q = lane + 64 * k;
            part += cross[(size_t)b * Tt * Qq + (size_t)(p_r[k] - 1) * Qq + q];
        }
    }
    for (int off = 32; off > 0; off >>= 1) part += __shfl_down(part, off);
    if (lane == 0) atomicAdd(out, part);
}

extern "C" void kernel_launch(void* const* d_in, const int* in_sizes, int n_in,
                              void* d_out, int out_size, void* d_ws, size_t ws_size,
                              hipStream_t stream) {
    const float* logits  = (const float*)d_in[0];   // [32,300,92] f32
    const float* pboxes  = (const float*)d_in[1];   // [32,300,4]  f32
    const int*   tlabels = (const int*)d_in[2];     // [1024]      int
    const float* tboxes  = (const float*)d_in[3];   // [1024,4]    f32
    float* out = (float*)d_out;                     // scalar f32
    float* diag  = (float*)d_ws;                            // [32,32,300]
    float* cross = (float*)d_ws + (size_t)Nn * Tt * Qq;     // [32,32,300]

    hipMemsetAsync(out, 0, sizeof(float), stream);
    cost_kernel<<<Nn, 320, 0, stream>>>(logits, pboxes, tlabels, tboxes, diag, cross);
    lsa_kernel<<<Nn, 64, 0, stream>>>(diag, cross, out);
}

// Round 4
// 118.221 us; speedup vs baseline: 1.7163x; 1.1081x over previous
//
#include <hip/hip_runtime.h>
#include <cfloat>

// Problem constants (from reference)
#define Nn 32
#define Qq 300
#define Cc 92
#define Tt 32
#define KCOLS 5   // ceil(300/64) columns owned per lane

// ---------------------------------------------------------------------------
// DPP full-wave (64-lane) float min, broadcast to all lanes.
// ---------------------------------------------------------------------------
__device__ inline float wave_min_bcast(float x) {
#define DPPMIN(ctrl) { int _t = __builtin_amdgcn_update_dpp( \
        __float_as_int(x), __float_as_int(x), ctrl, 0xf, 0xf, false); \
        x = fminf(x, __int_as_float(_t)); }
    DPPMIN(0x111) DPPMIN(0x112) DPPMIN(0x114) DPPMIN(0x118)
    DPPMIN(0x142) DPPMIN(0x143)
#undef DPPMIN
    return __int_as_float(__builtin_amdgcn_readlane(__float_as_int(x), 63));
}

// Select a[k] for runtime k (cndmask chain, no scratch).
__device__ inline int sel5i(const int a[KCOLS], int k) {
    int r = a[0];
    if (k == 1) r = a[1];
    if (k == 2) r = a[2];
    if (k == 3) r = a[3];
    if (k == 4) r = a[4];
    return r;
}

// Softmax stats over C=92 (single pass, 23 float4 loads). Must be the SAME
// code path for phase A and the post-pass so mx/inv_s match bit-for-bit.
__device__ inline void softmax92(const float* __restrict__ lg,
                                 float& mx, float& inv_s) {
    float4 r[23];
#pragma unroll
    for (int c = 0; c < 23; ++c) r[c] = reinterpret_cast<const float4*>(lg)[c];
    float m = -FLT_MAX;
#pragma unroll
    for (int c = 0; c < 23; ++c)
        m = fmaxf(m, fmaxf(fmaxf(r[c].x, r[c].y), fmaxf(r[c].z, r[c].w)));
    float s = 0.f;
#pragma unroll
    for (int c = 0; c < 23; ++c)
        s += __expf(r[c].x - m) + __expf(r[c].y - m) +
             __expf(r[c].z - m) + __expf(r[c].w - m);
    mx = m; inv_s = 1.f / s;
}

// cost = 5*L1 + cls - 2*giou   (cls = -softmax_prob[label], passed in)
__device__ inline float det_cost(float cx, float cy, float w, float h,
                                 float bcx, float bcy, float bw, float bh,
                                 float cls) {
    const float ax0 = cx - 0.5f * w, ay0 = cy - 0.5f * h;
    const float ax1 = cx + 0.5f * w, ay1 = cy + 0.5f * h;
    const float areaA = (ax1 - ax0) * (ay1 - ay0);

    const float l1 = fabsf(cx - bcx) + fabsf(cy - bcy) +
                     fabsf(w - bw) + fabsf(h - bh);

    const float bx0 = bcx - 0.5f * bw, by0 = bcy - 0.5f * bh;
    const float bx1 = bcx + 0.5f * bw, by1 = bcy + 0.5f * bh;
    const float areaB = (bx1 - bx0) * (by1 - by0);

    const float ltx = fmaxf(ax0, bx0), lty = fmaxf(ay0, by0);
    const float rbx = fminf(ax1, bx1), rby = fminf(ay1, by1);
    const float iw = fmaxf(rbx - ltx, 0.f), ih = fmaxf(rby - lty, 0.f);
    const float inter = iw * ih;
    const float uni = areaA + areaB - inter;
    const float iou = inter / uni;

    const float ex0 = fminf(ax0, bx0), ey0 = fminf(ay0, by0);
    const float ex1 = fmaxf(ax1, bx1), ey1 = fmaxf(ay1, by1);
    const float areaC = fmaxf(ex1 - ex0, 0.f) * fmaxf(ey1 - ey0, 0.f);
    const float giou = iou - (areaC - uni) / areaC;

    return 5.f * l1 + cls - 2.f * giou;
}

// ---------------------------------------------------------------------------
// Fused kernel: one block per batch.
//  Phase A (320 threads): diag cost block -> LDS (no global round-trip).
//  Phase B (wave 0): deferred-dual JV LSA on LDS block, register column state.
//  Phase C (lanes 0-31): recompute ONLY the 32 matched cross costs
//    (reference quirk: mult[i, q_of_t, arange(T)] gathers against GLOBAL
//    targets 0..31) and atomicAdd the partial sum.
// ---------------------------------------------------------------------------
__global__ __launch_bounds__(320) void fused_kernel(
    const float* __restrict__ logits,   // [N,Q,C]
    const float* __restrict__ pboxes,   // [N,Q,4]
    const int*   __restrict__ tlabels,  // [N*T]
    const float* __restrict__ tboxes,   // [N*T,4]
    float* __restrict__ out)            // scalar accumulator (pre-zeroed)
{
    const int b = blockIdx.x;
    const int tid = threadIdx.x;

    __shared__ float s_diag[Tt * Qq];   // 38400 B, [t][q]
    __shared__ float s_tb[Tt * 4];      // batch-b targets
    __shared__ int   s_tl[Tt];
    __shared__ float u[Tt + 1];
    __shared__ int   pairs[Tt];         // q_of_t

    if (tid < Tt * 4) s_tb[tid] = tboxes[b * Tt * 4 + tid];
    if (tid < Tt)     s_tl[tid] = tlabels[b * Tt + tid];
    __syncthreads();

    // ---------------- Phase A: diag costs into LDS ----------------
    if (tid < Qq) {
        const float* lg = logits + (size_t)(b * Qq + tid) * Cc;
        float mx, inv_s;
        softmax92(lg, mx, inv_s);
        const float4 pbv = reinterpret_cast<const float4*>(pboxes)[b * Qq + tid];
        for (int t = 0; t < Tt; ++t) {
            const float cls = -__expf(lg[s_tl[t]] - mx) * inv_s;
            s_diag[t * Qq + tid] =
                det_cost(pbv.x, pbv.y, pbv.z, pbv.w,
                         s_tb[t * 4 + 0], s_tb[t * 4 + 1],
                         s_tb[t * 4 + 2], s_tb[t * 4 + 3], cls);
        }
    }
    __syncthreads();      // all 320 threads reach this

    if (tid >= 64) return;            // waves 1-4 done; no barriers below
    const int lane = tid;

    // ---------------- Phase B: JV LSA (single wave) ----------------
    if (lane <= Tt) u[lane] = 0.f;
    __threadfence_block();

    float v_r[KCOLS], minv_r[KCOLS];
    int way_r[KCOLS], p_r[KCOLS], used_r[KCOLS];
    bool valid[KCOLS];
#pragma unroll
    for (int k = 0; k < KCOLS; ++k) {
        valid[k] = (lane + 64 * k) < Qq;
        v_r[k] = 0.f; p_r[k] = 0;
    }

    for (int i = 1; i <= Tt; ++i) {
#pragma unroll
        for (int k = 0; k < KCOLS; ++k) { minv_r[k] = FLT_MAX; way_r[k] = 0; used_r[k] = 0; }

        int   j0 = 0;
        int   i0 = i;
        float du = 0.f - u[i0];   // dent - u[i0] (deferred duals)
        int   jfinal = 0;
        float Dfinal = 0.f;

        while (true) {
            // scan free columns; update minv; local candidate
            float val = FLT_MAX;
            int idx = 0, kb = 0;
            const int rowbase = (i0 - 1) * Qq;
#pragma unroll
            for (int k = 0; k < KCOLS; ++k) {
                if (valid[k] && !used_r[k]) {
                    const int j = lane + 64 * k;
                    const float cur = s_diag[rowbase + j] + du - v_r[k];
                    if (cur < minv_r[k]) { minv_r[k] = cur; way_r[k] = j0; }
                    if (minv_r[k] < val) { val = minv_r[k]; idx = j + 1; kb = k; }
                }
            }
            // wave argmin + fetch (matched row, col) of the winner in one hop
            const float gmin = wave_min_bcast(val);
            const unsigned long long mask = __ballot(val == gmin);
            const int src = __ffsll((long long)mask) - 1;
            const unsigned long long pk =
                ((unsigned long long)(unsigned)sel5i(p_r, kb) << 32) | (unsigned)idx;
            const unsigned long long got = __shfl(pk, src);
            const int j1   = (int)(got & 0xffffffffu);
            const int rowm = (int)(got >> 32);

            // mark j1 used at its owner lane
            const int k1 = (j1 - 1) >> 6;
            const bool own = (lane == ((j1 - 1) & 63));
#pragma unroll
            for (int k = 0; k < KCOLS; ++k) if (own && k == k1) used_r[k] = 1;

            if (rowm == 0) { jfinal = j1; Dfinal = gmin; break; }
            j0 = j1; i0 = rowm; du = gmin - u[i0];
        }

        // dual updates (pre-augment p), once per row
#pragma unroll
        for (int k = 0; k < KCOLS; ++k) {
            if (used_r[k]) {
                const float dm = Dfinal - minv_r[k];
                v_r[k] -= dm;
                u[p_r[k]] += dm;          // distinct rows -> no collisions
            }
        }
        if (lane == 0) u[i] += Dfinal;
        __threadfence_block();            // u visible to next row's reads

        // augment along the path (register/shuffle walk; usually 1 hop)
        int jj = jfinal;
        while (jj) {
            const int ow = (jj - 1) & 63, kk = (jj - 1) >> 6;
            const int jprev = __shfl(sel5i(way_r, kk), ow);   // uniform
            int pnew;
            if (jprev == 0) pnew = i;
            else {
                const int ow2 = (jprev - 1) & 63, k2 = (jprev - 1) >> 6;
                pnew = __shfl(sel5i(p_r, k2), ow2);
            }
            const bool own = (lane == ow);
#pragma unroll
            for (int k = 0; k < KCOLS; ++k) if (own && k == kk) p_r[k] = pnew;
            jj = jprev;
        }
    }

    // publish assignment: q_of_t
#pragma unroll
    for (int k = 0; k < KCOLS; ++k)
        if (valid[k] && p_r[k]) pairs[p_r[k] - 1] = lane + 64 * k;
    __threadfence_block();

    // ---------------- Phase C: 32 matched cross costs ----------------
    float part = 0.f;
    if (lane < Tt) {
        const int q = pairs[lane];                        // matched query
        const float* lg = logits + (size_t)(b * Qq + q) * Cc;
        float mx, inv_s;
        softmax92(lg, mx, inv_s);                          // identical path to phase A
        const float4 pbv = reinterpret_cast<const float4*>(pboxes)[b * Qq + q];
        const float4 tbv = reinterpret_cast<const float4*>(tboxes)[lane];  // GLOBAL target t=lane
        const int   label = tlabels[lane];
        const float cls = -__expf(lg[label] - mx) * inv_s;
        part = det_cost(pbv.x, pbv.y, pbv.z, pbv.w,
                        tbv.x, tbv.y, tbv.z, tbv.w, cls);
    }
    for (int off = 32; off > 0; off >>= 1) part += __shfl_down(part, off);
    if (lane == 0) atomicAdd(out, part);
}

extern "C" void kernel_launch(void* const* d_in, const int* in_sizes, int n_in,
                              void* d_out, int out_size, void* d_ws, size_t ws_size,
                              hipStream_t stream) {
    const float* logits  = (const float*)d_in[0];   // [32,300,92] f32
    const float* pboxes  = (const float*)d_in[1];   // [32,300,4]  f32
    const int*   tlabels = (const int*)d_in[2];     // [1024]      int
    const float* tboxes  = (const float*)d_in[3];   // [1024,4]    f32
    float* out = (float*)d_out;                     // scalar f32

    hipMemsetAsync(out, 0, sizeof(float), stream);
    fused_kernel<<<Nn, 320, 0, stream>>>(logits, pboxes, tlabels, tboxes, out);
}

// Round 5
// 113.722 us; speedup vs baseline: 1.7842x; 1.0396x over previous
//
#include <hip/hip_runtime.h>
#include <cfloat>

// Problem constants (from reference)
#define Nn 32
#define Qq 300
#define Cc 92
#define Tt 32
#define KCOLS 5   // ceil(300/64) columns owned per lane

// ---------------------------------------------------------------------------
// DPP full-wave (64-lane) float min, broadcast to all lanes (~6 dep. v_min).
// ---------------------------------------------------------------------------
__device__ inline float wave_min_bcast(float x) {
#define DPPMIN(ctrl) { int _t = __builtin_amdgcn_update_dpp( \
        __float_as_int(x), __float_as_int(x), ctrl, 0xf, 0xf, false); \
        x = fminf(x, __int_as_float(_t)); }
    DPPMIN(0x111) DPPMIN(0x112) DPPMIN(0x114) DPPMIN(0x118)
    DPPMIN(0x142) DPPMIN(0x143)
#undef DPPMIN
    return __int_as_float(__builtin_amdgcn_readlane(__float_as_int(x), 63));
}

// Select a[k] for runtime k (cndmask chain, no scratch).
__device__ inline int sel5i(const int a[KCOLS], int k) {
    int r = a[0];
    if (k == 1) r = a[1];
    if (k == 2) r = a[2];
    if (k == 3) r = a[3];
    if (k == 4) r = a[4];
    return r;
}

__device__ inline float readlane_f(float v, int lane) {
    return __int_as_float(__builtin_amdgcn_readlane(__float_as_int(v), lane));
}

// Softmax stats over C=92 (single pass, 23 float4 loads). SAME code path for
// phase A and phase C so mx/inv_s match bit-for-bit.
__device__ inline void softmax92(const float* __restrict__ lg,
                                 float& mx, float& inv_s) {
    float4 r[23];
#pragma unroll
    for (int c = 0; c < 23; ++c) r[c] = reinterpret_cast<const float4*>(lg)[c];
    float m = -FLT_MAX;
#pragma unroll
    for (int c = 0; c < 23; ++c)
        m = fmaxf(m, fmaxf(fmaxf(r[c].x, r[c].y), fmaxf(r[c].z, r[c].w)));
    float s = 0.f;
#pragma unroll
    for (int c = 0; c < 23; ++c)
        s += __expf(r[c].x - m) + __expf(r[c].y - m) +
             __expf(r[c].z - m) + __expf(r[c].w - m);
    mx = m; inv_s = 1.f / s;
}

// cost = 5*L1 + cls - 2*giou   (cls = -softmax_prob[label], passed in)
__device__ inline float det_cost(float cx, float cy, float w, float h,
                                 float bcx, float bcy, float bw, float bh,
                                 float cls) {
    const float ax0 = cx - 0.5f * w, ay0 = cy - 0.5f * h;
    const float ax1 = cx + 0.5f * w, ay1 = cy + 0.5f * h;
    const float areaA = (ax1 - ax0) * (ay1 - ay0);

    const float l1 = fabsf(cx - bcx) + fabsf(cy - bcy) +
                     fabsf(w - bw) + fabsf(h - bh);

    const float bx0 = bcx - 0.5f * bw, by0 = bcy - 0.5f * bh;
    const float bx1 = bcx + 0.5f * bw, by1 = bcy + 0.5f * bh;
    const float areaB = (bx1 - bx0) * (by1 - by0);

    const float ltx = fmaxf(ax0, bx0), lty = fmaxf(ay0, by0);
    const float rbx = fminf(ax1, bx1), rby = fminf(ay1, by1);
    const float iw = fmaxf(rbx - ltx, 0.f), ih = fmaxf(rby - lty, 0.f);
    const float inter = iw * ih;
    const float uni = areaA + areaB - inter;
    const float iou = inter / uni;

    const float ex0 = fminf(ax0, bx0), ey0 = fminf(ay0, by0);
    const float ex1 = fmaxf(ax1, bx1), ey1 = fmaxf(ay1, by1);
    const float areaC = fmaxf(ex1 - ex0, 0.f) * fmaxf(ey1 - ey0, 0.f);
    const float giou = iou - (areaC - uni) / areaC;

    return 5.f * l1 + cls - 2.f * giou;
}

// ---------------------------------------------------------------------------
// Fused kernel: one block per batch.
//  Phase A (320 threads): diag cost block -> LDS.
//  Phase B (wave 0): deferred-dual JV LSA; column state in registers,
//    u in lane-registers, all cross-lane traffic via readlane (uniform idx).
//  Phase C (lanes 0-31): the 32 matched CROSS costs (reference quirk:
//    mult[i, q_of_t, arange(T)] gathers against GLOBAL targets 0..31).
// ---------------------------------------------------------------------------
__global__ __launch_bounds__(320) void fused_kernel(
    const float* __restrict__ logits,   // [N,Q,C]
    const float* __restrict__ pboxes,   // [N,Q,4]
    const int*   __restrict__ tlabels,  // [N*T]
    const float* __restrict__ tboxes,   // [N*T,4]
    float* __restrict__ out)            // scalar accumulator (pre-zeroed)
{
    const int b = blockIdx.x;
    const int tid = threadIdx.x;

    __shared__ float s_diag[Tt * Qq];   // 38400 B, [t][q]
    __shared__ float s_tb[Tt * 4];      // batch-b targets
    __shared__ int   s_tl[Tt];
    __shared__ float dm_lds[Tt + 1];    // per-row dual-update staging
    __shared__ int   pairs[Tt];         // q_of_t

    if (tid < Tt * 4) s_tb[tid] = tboxes[b * Tt * 4 + tid];
    if (tid < Tt)     s_tl[tid] = tlabels[b * Tt + tid];
    __syncthreads();

    // ---------------- Phase A: diag costs into LDS ----------------
    if (tid < Qq) {
        const float* lg = logits + (size_t)(b * Qq + tid) * Cc;
        float mx, inv_s;
        softmax92(lg, mx, inv_s);
        const float4 pbv = reinterpret_cast<const float4*>(pboxes)[b * Qq + tid];
        for (int t = 0; t < Tt; ++t) {
            const float cls = -__expf(lg[s_tl[t]] - mx) * inv_s;
            s_diag[t * Qq + tid] =
                det_cost(pbv.x, pbv.y, pbv.z, pbv.w,
                         s_tb[t * 4 + 0], s_tb[t * 4 + 1],
                         s_tb[t * 4 + 2], s_tb[t * 4 + 3], cls);
        }
    }
    __syncthreads();      // all 320 threads reach this

    if (tid >= 64) return;            // waves 1-4 done; single wave below
    const int lane = tid;

    // ---------------- Phase B: JV LSA (single wave) ----------------
    float u_reg = 0.f;                // lane t holds u[t] (t=1..32)
    float v_r[KCOLS], minv_r[KCOLS];
    int way_r[KCOLS], p_r[KCOLS], used_r[KCOLS];
    const int inval4 = (lane + 256) >= Qq;   // only k=4 can be out of range
#pragma unroll
    for (int k = 0; k < KCOLS; ++k) { v_r[k] = 0.f; p_r[k] = 0; }

    for (int i = 1; i <= Tt; ++i) {
#pragma unroll
        for (int k = 0; k < KCOLS; ++k) {
            minv_r[k] = FLT_MAX; way_r[k] = 0;
            used_r[k] = (k == 4) ? inval4 : 0;
        }

        int   j0 = 0;
        int   i0 = i;
        float du = 0.f;          // dent - u[i0]; u[i]==0 for the fresh row
        int   jfinal = 0;
        float Dfinal = 0.f;

        while (true) {
            // scan free columns; update minv; local candidate
            float val = FLT_MAX;
            int idx = 0, kb = 0;
            const int rowbase = (i0 - 1) * Qq;
#pragma unroll
            for (int k = 0; k < KCOLS; ++k) {
                if (!used_r[k]) {
                    const int j = lane + 64 * k;
                    const float cur = s_diag[rowbase + j] + du - v_r[k];
                    if (cur < minv_r[k]) { minv_r[k] = cur; way_r[k] = j0; }
                    if (minv_r[k] < val) { val = minv_r[k]; idx = j + 1; kb = k; }
                }
            }
            // wave argmin; winner's (matched row, col) via one 32-bit readlane
            const float gmin = wave_min_bcast(val);
            const unsigned long long mask = __ballot(val == gmin);
            const int src = __ffsll((long long)mask) - 1;
            const int pk = (sel5i(p_r, kb) << 16) | idx;      // row<=32, col<=300
            const int got = __builtin_amdgcn_readlane(pk, src);
            const int j1   = got & 0xffff;
            const int rowm = got >> 16;

            // mark j1 used at its owner lane
            const int k1 = (j1 - 1) >> 6;
            const bool own = (lane == ((j1 - 1) & 63));
#pragma unroll
            for (int k = 0; k < KCOLS; ++k) if (own && k == k1) used_r[k] = 1;

            if (rowm == 0) { jfinal = j1; Dfinal = gmin; break; }
            j0 = j1; i0 = rowm;
            du = gmin - readlane_f(u_reg, i0);   // dent - u[i0], register-speed
        }

        // ---- dual updates, once per row (off the critical inner loop) ----
        if (lane <= Tt) dm_lds[lane] = 0.f;
        __threadfence_block();
#pragma unroll
        for (int k = 0; k < KCOLS; ++k) {
            if (used_r[k]) {
                const float dm = Dfinal - minv_r[k];
                v_r[k] -= dm;
                dm_lds[p_r[k]] = dm;   // distinct rows; jfinal scatters dm=0 to slot 0
            }
        }
        __threadfence_block();
        if (lane <= Tt) u_reg += (lane == i) ? Dfinal : dm_lds[lane];

        // ---- augment along the path (readlane walk; usually 1 hop) ----
        int jj = jfinal;
        while (jj) {
            const int ow = (jj - 1) & 63, kk = (jj - 1) >> 6;
            const int jprev = __builtin_amdgcn_readlane(sel5i(way_r, kk), ow);
            int pnew;
            if (jprev == 0) pnew = i;
            else pnew = __builtin_amdgcn_readlane(sel5i(p_r, (jprev - 1) >> 6),
                                                  (jprev - 1) & 63);
            const bool own = (lane == ow);
#pragma unroll
            for (int k = 0; k < KCOLS; ++k) if (own && k == kk) p_r[k] = pnew;
            jj = jprev;
        }
    }

    // publish assignment: q_of_t
#pragma unroll
    for (int k = 0; k < KCOLS; ++k)
        if (p_r[k]) pairs[p_r[k] - 1] = lane + 64 * k;
    __threadfence_block();

    // ---------------- Phase C: 32 matched cross costs ----------------
    float part = 0.f;
    if (lane < Tt) {
        const int q = pairs[lane];                        // matched query
        const float* lg = logits + (size_t)(b * Qq + q) * Cc;
        float mx, inv_s;
        softmax92(lg, mx, inv_s);                          // identical path to phase A
        const float4 pbv = reinterpret_cast<const float4*>(pboxes)[b * Qq + q];
        const float4 tbv = reinterpret_cast<const float4*>(tboxes)[lane];  // GLOBAL t=lane
        const float cls = -__expf(lg[tlabels[lane]] - mx) * inv_s;
        part = det_cost(pbv.x, pbv.y, pbv.z, pbv.w,
                        tbv.x, tbv.y, tbv.z, tbv.w, cls);
    }
    for (int off = 32; off > 0; off >>= 1) part += __shfl_down(part, off);
    if (lane == 0) atomicAdd(out, part);
}

extern "C" void kernel_launch(void* const* d_in, const int* in_sizes, int n_in,
                              void* d_out, int out_size, void* d_ws, size_t ws_size,
                              hipStream_t stream) {
    const float* logits  = (const float*)d_in[0];   // [32,300,92] f32
    const float* pboxes  = (const float*)d_in[1];   // [32,300,4]  f32
    const int*   tlabels = (const int*)d_in[2];     // [1024]      int
    const float* tboxes  = (const float*)d_in[3];   // [1024,4]    f32
    float* out = (float*)d_out;                     // scalar f32

    hipMemsetAsync(out, 0, sizeof(float), stream);
    fused_kernel<<<Nn, 320, 0, stream>>>(logits, pboxes, tlabels, tboxes, out);
}